// Round 9
// baseline (128.406 us; speedup 1.0000x reference)
//
#include <hip/hip_runtime.h>

#define N_NODES 256
#define F_DIM   16
#define H_DIM   2048
#define P_DIM   16
#define E_EDGES 32768

// ---------------------------------------------------------------------------
// ONE kernel, one block per node, 512 threads, ZERO cross-block communication.
// Algebra: out = A@(x@W)+b == (A@x)@W+b (K collapses 2048->16):
//   g[n][f] = dinv[n]*( sum_{e:dst=n} dinv[src] x[src][f] + dinv[n] x[n][f] )
//   o[n][h] = sum_f g[n][f] W[f][h] + b[h]
//   q[n][p] = sum_h o[n][h] Wq[n][h][p] + bq[n][p]
// R8 lesson (Little's law): the Wq stream ran at 350 GB/s because only ~4
// float4/wave were in flight. Fix: batch ALL 16 float4 Wq loads into regs
// (64 VGPRs held on purpose) and issue them before the filter/o phases.
// ---------------------------------------------------------------------------
__global__ __launch_bounds__(512) void k_one(
    const float* __restrict__ x, const int* __restrict__ ei,
    const float* __restrict__ W, const float* __restrict__ b,
    const float* __restrict__ Wq, const float* __restrict__ bq,
    float* __restrict__ qout)
{
    __shared__ float xlT[F_DIM][N_NODES];  // x transposed: conflict-free reads
    __shared__ int   degs[N_NODES];
    __shared__ float dinv[N_NODES];
    __shared__ float g[F_DIM];
    __shared__ float red[8][P_DIM];

    const int n = blockIdx.x;
    const int t = threadIdx.x;

    // ---- P0: stage x -> LDS (transposed), zero histogram + g
    if (t < 256) {
        degs[t] = 0;
        const float4* x4 = (const float4*)(x + t * F_DIM);
        float4 a0 = x4[0], a1 = x4[1], a2 = x4[2], a3 = x4[3];
        xlT[0][t]  = a0.x; xlT[1][t]  = a0.y; xlT[2][t]  = a0.z; xlT[3][t]  = a0.w;
        xlT[4][t]  = a1.x; xlT[5][t]  = a1.y; xlT[6][t]  = a1.z; xlT[7][t]  = a1.w;
        xlT[8][t]  = a2.x; xlT[9][t]  = a2.y; xlT[10][t] = a2.z; xlT[11][t] = a2.w;
        xlT[12][t] = a3.x; xlT[13][t] = a3.y; xlT[14][t] = a3.z; xlT[15][t] = a3.w;
    }
    if (t < F_DIM) g[t] = 0.0f;
    __syncthreads();

    // ---- P1: histogram ALL dst into LDS. 64 edges/thread as 4 groups of
    // 4x int4 (loads batched per group, regs freed after use).
    const int4* dst4 = (const int4*)(ei + E_EDGES);
    const int4* src4 = (const int4*)ei;
#pragma unroll
    for (int gup = 0; gup < 4; ++gup) {
        int4 d0 = dst4[(gup * 4 + 0) * 512 + t];
        int4 d1 = dst4[(gup * 4 + 1) * 512 + t];
        int4 d2 = dst4[(gup * 4 + 2) * 512 + t];
        int4 d3 = dst4[(gup * 4 + 3) * 512 + t];
        atomicAdd(&degs[d0.x], 1); atomicAdd(&degs[d0.y], 1);
        atomicAdd(&degs[d0.z], 1); atomicAdd(&degs[d0.w], 1);
        atomicAdd(&degs[d1.x], 1); atomicAdd(&degs[d1.y], 1);
        atomicAdd(&degs[d1.z], 1); atomicAdd(&degs[d1.w], 1);
        atomicAdd(&degs[d2.x], 1); atomicAdd(&degs[d2.y], 1);
        atomicAdd(&degs[d2.z], 1); atomicAdd(&degs[d2.w], 1);
        atomicAdd(&degs[d3.x], 1); atomicAdd(&degs[d3.y], 1);
        atomicAdd(&degs[d3.z], 1); atomicAdd(&degs[d3.w], 1);
    }
    __syncthreads();

    // ---- dinv = rsqrt(deg+1)  (+1 self-loop)
    if (t < 256)
        dinv[t] = rsqrtf((float)degs[t] + 1.0f);
    __syncthreads();

    // ---- issue the FULL Wq stream now (16 float4 = 1 KB/lane in flight);
    // consumed only after the graph phases -> latency overlaps P2/o.
    const float* Wqn = Wq + (size_t)n * H_DIM * P_DIM;
    float4 wq[16];
#pragma unroll
    for (int i = 0; i < 4; ++i) {
        int hh = i * 512 + t;
        const float4* p4 = (const float4*)(Wqn + (size_t)hh * P_DIM);
        wq[4 * i + 0] = p4[0];
        wq[4 * i + 1] = p4[1];
        wq[4 * i + 2] = p4[2];
        wq[4 * i + 3] = p4[3];
    }

    // ---- P2: filter my in-edges; load src+dst together (no dependent load)
#pragma unroll
    for (int gup = 0; gup < 4; ++gup) {
#pragma unroll
        for (int v = 0; v < 4; ++v) {
            int k = (gup * 4 + v) * 512 + t;
            int4 dd = dst4[k];
            int4 ss = src4[k];
            if (dd.x == n) { float a = dinv[ss.x];
#pragma unroll
                for (int f = 0; f < F_DIM; ++f) atomicAdd(&g[f], a * xlT[f][ss.x]); }
            if (dd.y == n) { float a = dinv[ss.y];
#pragma unroll
                for (int f = 0; f < F_DIM; ++f) atomicAdd(&g[f], a * xlT[f][ss.y]); }
            if (dd.z == n) { float a = dinv[ss.z];
#pragma unroll
                for (int f = 0; f < F_DIM; ++f) atomicAdd(&g[f], a * xlT[f][ss.z]); }
            if (dd.w == n) { float a = dinv[ss.w];
#pragma unroll
                for (int f = 0; f < F_DIM; ++f) atomicAdd(&g[f], a * xlT[f][ss.w]); }
        }
    }
    __syncthreads();

    // ---- gr[f] = (g[f] + dinv[n]*x[n][f]) * dinv[n]
    const float dn = dinv[n];
    float gr[F_DIM];
#pragma unroll
    for (int f = 0; f < F_DIM; ++f)
        gr[f] = (g[f] + dn * xlT[f][n]) * dn;

    // ---- o[i] = b[hh] + sum_f gr[f]*W[f][hh],  hh = i*512 + t (coalesced)
    float o[4];
#pragma unroll
    for (int i = 0; i < 4; ++i) {
        int hh = i * 512 + t;
        float v = b[hh];
#pragma unroll
        for (int f = 0; f < F_DIM; ++f)
            v += gr[f] * W[f * H_DIM + hh];
        o[i] = v;
    }

    // ---- consume the prefetched Wq registers
    float acc[16];
#pragma unroll
    for (int p = 0; p < 16; ++p) acc[p] = 0.0f;
#pragma unroll
    for (int i = 0; i < 4; ++i) {
        float ov = o[i];
        float4 u0 = wq[4 * i + 0], u1 = wq[4 * i + 1];
        float4 u2 = wq[4 * i + 2], u3 = wq[4 * i + 3];
        acc[0]  += ov * u0.x; acc[1]  += ov * u0.y; acc[2]  += ov * u0.z; acc[3]  += ov * u0.w;
        acc[4]  += ov * u1.x; acc[5]  += ov * u1.y; acc[6]  += ov * u1.z; acc[7]  += ov * u1.w;
        acc[8]  += ov * u2.x; acc[9]  += ov * u2.y; acc[10] += ov * u2.z; acc[11] += ov * u2.w;
        acc[12] += ov * u3.x; acc[13] += ov * u3.y; acc[14] += ov * u3.z; acc[15] += ov * u3.w;
    }

    // ---- wave butterfly (64 lanes) then cross-wave via LDS
#pragma unroll
    for (int p = 0; p < 16; ++p)
#pragma unroll
        for (int off = 32; off > 0; off >>= 1)
            acc[p] += __shfl_down(acc[p], off, 64);

    const int w = t >> 6, l = t & 63;
    if (l == 0) {
#pragma unroll
        for (int p = 0; p < 16; ++p) red[w][p] = acc[p];
    }
    __syncthreads();
    if (t < P_DIM) {
        float s = red[0][t] + red[1][t] + red[2][t] + red[3][t] +
                  red[4][t] + red[5][t] + red[6][t] + red[7][t] +
                  bq[n * P_DIM + t];
        qout[n * P_DIM + t] = s;
    }
}

extern "C" void kernel_launch(void* const* d_in, const int* in_sizes, int n_in,
                              void* d_out, int out_size, void* d_ws, size_t ws_size,
                              hipStream_t stream) {
    const float* x  = (const float*)d_in[0];  // [256,16]
    const int*   ei = (const int*)d_in[1];    // [2,32768]
    const float* W  = (const float*)d_in[2];  // [16,2048]
    const float* b  = (const float*)d_in[3];  // [2048]
    const float* Wq = (const float*)d_in[4];  // [256,2048,16]
    const float* bq = (const float*)d_in[5];  // [256,16]
    float* qout = (float*)d_out;              // [256,16]

    k_one<<<N_NODES, 512, 0, stream>>>(x, ei, W, b, Wq, bq, qout);
}

// Round 10
// 116.530 us; speedup vs baseline: 1.1019x; 1.1019x over previous
//
#include <hip/hip_runtime.h>

#define N_NODES 256
#define F_DIM   16
#define H_DIM   2048
#define P_DIM   16
#define E_EDGES 32768
#define K1_BLOCKS 32

// ---------------------------------------------------------------------------
// R9 post-mortem: per-block redundant histogram (8.4M LDS atomics device-wide,
// serialized on each CU's DS pipe) dominated the 54 µs — not the Wq stream
// (FETCH=19.4MB < Wq's 33.5MB: Wq is L3-resident). New split:
//   K1: 32 blocks x 1024 thr, private LDS histogram of 1024 edges each,
//       PLAIN stores of partials to ws (no zeroing, overwrites poison).
//   K2: 256 blocks x 1024 thr: deg = sum of 32 partials; filter own in-edges
//       (~128 hits -> ~2K LDS atomics, not 32K); o in regs; batched Wq stream.
// Algebra unchanged: out=(A@x)@W+b, q = einsum(out,Wq)+bq.
// ---------------------------------------------------------------------------

__global__ __launch_bounds__(1024) void k_hist(const int* __restrict__ ei,
                                               float* __restrict__ part) {
    __shared__ int hist[N_NODES];
    const int t = threadIdx.x, b = blockIdx.x;
    if (t < 256) hist[t] = 0;
    __syncthreads();
    atomicAdd(&hist[ei[E_EDGES + b * 1024 + t]], 1);   // one edge per thread
    __syncthreads();
    if (t < 256) part[b * 256 + t] = (float)hist[t];   // plain store over poison
}

__global__ __launch_bounds__(1024) void k_main(
    const float* __restrict__ part, const float* __restrict__ x,
    const int* __restrict__ ei, const float* __restrict__ W,
    const float* __restrict__ b, const float* __restrict__ Wq,
    const float* __restrict__ bq, float* __restrict__ qout)
{
    __shared__ float xlT[F_DIM][N_NODES];   // x transposed: conflict-free reads
    __shared__ float dinv[N_NODES];
    __shared__ float g[F_DIM];
    __shared__ float red[16][P_DIM];

    const int n = blockIdx.x;
    const int t = threadIdx.x;

    // ---- P0: stage x -> LDS (transposed); deg from 32 partials -> dinv
    if (t < 256) {
        const float4* x4 = (const float4*)(x + t * F_DIM);
        float4 a0 = x4[0], a1 = x4[1], a2 = x4[2], a3 = x4[3];
        xlT[0][t]  = a0.x; xlT[1][t]  = a0.y; xlT[2][t]  = a0.z; xlT[3][t]  = a0.w;
        xlT[4][t]  = a1.x; xlT[5][t]  = a1.y; xlT[6][t]  = a1.z; xlT[7][t]  = a1.w;
        xlT[8][t]  = a2.x; xlT[9][t]  = a2.y; xlT[10][t] = a2.z; xlT[11][t] = a2.w;
        xlT[12][t] = a3.x; xlT[13][t] = a3.y; xlT[14][t] = a3.z; xlT[15][t] = a3.w;
        float s = 1.0f;                      // +1 self-loop
#pragma unroll
        for (int j = 0; j < K1_BLOCKS; ++j)  // 32 independent coalesced loads
            s += part[j * 256 + t];
        dinv[t] = rsqrtf(s);
    }
    if (t < F_DIM) g[t] = 0.0f;
    __syncthreads();

    // ---- issue the FULL Wq slice now: 8 float4/thread (hh = t and t+1024)
    const float* Wqn = Wq + (size_t)n * H_DIM * P_DIM;
    const float4* w4a = (const float4*)(Wqn + (size_t)t * P_DIM);
    const float4* w4b = (const float4*)(Wqn + (size_t)(t + 1024) * P_DIM);
    float4 wq[8];
    wq[0] = w4a[0]; wq[1] = w4a[1]; wq[2] = w4a[2]; wq[3] = w4a[3];
    wq[4] = w4b[0]; wq[5] = w4b[1]; wq[6] = w4b[2]; wq[7] = w4b[3];

    // ---- P2: filter my in-edges (32 edges/thread, src+dst paired loads)
    const int4* dst4 = (const int4*)(ei + E_EDGES);
    const int4* src4 = (const int4*)ei;
#pragma unroll
    for (int gup = 0; gup < 2; ++gup) {
#pragma unroll
        for (int v = 0; v < 4; ++v) {
            int k = (gup * 4 + v) * 1024 + t;
            int4 dd = dst4[k];
            int4 ss = src4[k];
            if (dd.x == n) { float a = dinv[ss.x];
#pragma unroll
                for (int f = 0; f < F_DIM; ++f) atomicAdd(&g[f], a * xlT[f][ss.x]); }
            if (dd.y == n) { float a = dinv[ss.y];
#pragma unroll
                for (int f = 0; f < F_DIM; ++f) atomicAdd(&g[f], a * xlT[f][ss.y]); }
            if (dd.z == n) { float a = dinv[ss.z];
#pragma unroll
                for (int f = 0; f < F_DIM; ++f) atomicAdd(&g[f], a * xlT[f][ss.z]); }
            if (dd.w == n) { float a = dinv[ss.w];
#pragma unroll
                for (int f = 0; f < F_DIM; ++f) atomicAdd(&g[f], a * xlT[f][ss.w]); }
        }
    }
    __syncthreads();

    // ---- gr[f] = (g[f] + dinv[n]*x[n][f]) * dinv[n]
    const float dn = dinv[n];
    float gr[F_DIM];
#pragma unroll
    for (int f = 0; f < F_DIM; ++f)
        gr[f] = (g[f] + dn * xlT[f][n]) * dn;

    // ---- o[i] = b[hh] + sum_f gr[f]*W[f][hh],  hh = t, t+1024 (coalesced)
    float o[2];
#pragma unroll
    for (int i = 0; i < 2; ++i) {
        int hh = i * 1024 + t;
        float v = b[hh];
#pragma unroll
        for (int f = 0; f < F_DIM; ++f)
            v += gr[f] * W[f * H_DIM + hh];
        o[i] = v;
    }

    // ---- consume the prefetched Wq registers
    float acc[16];
#pragma unroll
    for (int p = 0; p < 16; ++p) acc[p] = 0.0f;
#pragma unroll
    for (int i = 0; i < 2; ++i) {
        float ov = o[i];
        float4 u0 = wq[4 * i + 0], u1 = wq[4 * i + 1];
        float4 u2 = wq[4 * i + 2], u3 = wq[4 * i + 3];
        acc[0]  += ov * u0.x; acc[1]  += ov * u0.y; acc[2]  += ov * u0.z; acc[3]  += ov * u0.w;
        acc[4]  += ov * u1.x; acc[5]  += ov * u1.y; acc[6]  += ov * u1.z; acc[7]  += ov * u1.w;
        acc[8]  += ov * u2.x; acc[9]  += ov * u2.y; acc[10] += ov * u2.z; acc[11] += ov * u2.w;
        acc[12] += ov * u3.x; acc[13] += ov * u3.y; acc[14] += ov * u3.z; acc[15] += ov * u3.w;
    }

    // ---- wave butterfly (64 lanes) then cross-wave via LDS (16 waves)
#pragma unroll
    for (int p = 0; p < 16; ++p)
#pragma unroll
        for (int off = 32; off > 0; off >>= 1)
            acc[p] += __shfl_down(acc[p], off, 64);

    const int w = t >> 6, l = t & 63;
    if (l == 0) {
#pragma unroll
        for (int p = 0; p < 16; ++p) red[w][p] = acc[p];
    }
    __syncthreads();
    if (t < P_DIM) {
        float s = bq[n * P_DIM + t];
#pragma unroll
        for (int j = 0; j < 16; ++j) s += red[j][t];
        qout[n * P_DIM + t] = s;
    }
}

extern "C" void kernel_launch(void* const* d_in, const int* in_sizes, int n_in,
                              void* d_out, int out_size, void* d_ws, size_t ws_size,
                              hipStream_t stream) {
    const float* x  = (const float*)d_in[0];  // [256,16]
    const int*   ei = (const int*)d_in[1];    // [2,32768]
    const float* W  = (const float*)d_in[2];  // [16,2048]
    const float* b  = (const float*)d_in[3];  // [2048]
    const float* Wq = (const float*)d_in[4];  // [256,2048,16]
    const float* bq = (const float*)d_in[5];  // [256,16]
    float* qout = (float*)d_out;              // [256,16]
    float* part = (float*)d_ws;               // 32*256 floats (32 KB)

    k_hist<<<K1_BLOCKS, 1024, 0, stream>>>(ei, part);
    k_main<<<N_NODES,  1024, 0, stream>>>(part, x, ei, W, b, Wq, bq, qout);
}